// Round 9
// baseline (120.929 us; speedup 1.0000x reference)
//
#include <hip/hip_runtime.h>
#include <hip/hip_bf16.h>

#define B_    128
#define H_    256
#define WI_   256
#define CIN   8
#define COUT  8
#define SS    64
#define RST   (WI_*CIN)     // 2048 f32 per input row
#define OST   (WI_*COUT)    // 2048 f32 per output row

typedef __attribute__((ext_vector_type(8))) short bh8;   // 8 bf16 (MFMA A/B frag)
typedef __attribute__((ext_vector_type(4))) float f4;    // MFMA C/D frag

static __device__ __forceinline__ unsigned short f2bf(float f) {
    union { __hip_bfloat16 h; unsigned short u; } c;
    c.h = __float2bfloat16(f);
    return c.u;
}

static __device__ __forceinline__ bh8 pack_mask(float4 lo, float4 hi, unsigned m) {
    union { bh8 v; unsigned short u[8]; unsigned w[4]; } r;
    r.u[0]=f2bf(lo.x); r.u[1]=f2bf(lo.y); r.u[2]=f2bf(lo.z); r.u[3]=f2bf(lo.w);
    r.u[4]=f2bf(hi.x); r.u[5]=f2bf(hi.y); r.u[6]=f2bf(hi.z); r.u[7]=f2bf(hi.w);
    r.w[0]&=m; r.w[1]&=m; r.w[2]&=m; r.w[3]&=m;
    return r.v;
}

// wave = 16-column output segment marching down SS rows.
// MFMA: D = Wfrag(A, M=cout) x Xfrag(B, N=pixel) + C
//   Wfrag[kh]: lane m=lane&15 (cout, 8 real), g=lane>>4 -> kw=g (g<3), k_j=ci
//   Xfrag(h'): lane p=lane&15 (pixel), g=lane>>4 -> col=w0+p+g-1, k_j=ci
//   D: lane p=lane&15 (pixel), couts 4g..4g+3 (g<2 real) -> dense float4 store
// Depth-3 prefetch via 4 rotating named row buffers (R0..R3), plain stores.
__global__ __launch_bounds__(256, 2)
void conv_mfma_kernel(const float* __restrict__ X,
                      const float* __restrict__ Wt,
                      const float* __restrict__ bias,
                      const float* __restrict__ Werr,
                      const float* __restrict__ Berr,
                      float* __restrict__ out)
{
    __shared__ float wlds[576];           // noisy weights, transposed [khkw][cout][cin]
    const int tid = threadIdx.x;
    const int b   = blockIdx.z;
    const int rs  = blockIdx.y * SS;

    {
        const float* we = Werr + (size_t)b * 576;
        for (int i = tid; i < 576; i += 256) {
            const int khkw = i >> 6, ci = (i >> 3) & 7, co = i & 7;
            wlds[(khkw * 8 + co) * 8 + ci] = Wt[i] * we[i];
        }
    }
    __syncthreads();

    const int lane = tid & 63, wid = tid >> 6;
    const int w0 = blockIdx.x * 64 + wid * 16;
    const int p  = lane & 15;             // pixel (B col / D col); cout slot for A
    const int g  = lane >> 4;             // k-group (kw) / D cout-quad index

    // ---- A fragments: weights, one per kh; zero for m>=8 or g==3 ----
    bh8 Wf0, Wf1, Wf2;
    {
        const float4 z4 = make_float4(0.f, 0.f, 0.f, 0.f);
        #pragma unroll
        for (int kh = 0; kh < 3; ++kh) {
            float4 lo = z4, hi = z4;
            if (p < 8 && g < 3) {
                const float* ptr = &wlds[((kh * 3 + g) * 8 + p) * 8];
                lo = *(const float4*)ptr;
                hi = *(const float4*)(ptr + 4);
            }
            const bh8 f = pack_mask(lo, hi, 0xffffffffu);
            if (kh == 0) Wf0 = f; else if (kh == 1) Wf1 = f; else Wf2 = f;
        }
    }

    // ---- bias fragment: D reg r holds cout 4*g+r (g<2) ----
    f4 biasF = {0.f, 0.f, 0.f, 0.f};
    if (g < 2) {
        #pragma unroll
        for (int r = 0; r < 4; ++r) {
            const int co = g * 4 + r;
            biasF[r] = bias[co] * Berr[(size_t)b * COUT + co];
        }
    }

    // ---- X (pixel) addressing: per-lane column, clamped + masked ----
    const int col = w0 + p + g - 1;
    const unsigned amask = ((unsigned)col < (unsigned)WI_ && g < 3) ? 0xffffffffu : 0u;
    const int colc = col < 0 ? 0 : (col > WI_ - 1 ? WI_ - 1 : col);
    const float* __restrict__ xb = X + (size_t)b * H_ * RST;
    int voff = (rs > 0 ? rs - 1 : rs) * RST + colc * CIN;

    float4 R00, R01, R10, R11, R20, R21, R30, R31;
    if (rs > 0) {                          // R0 <- row rs-1
        R00 = *(const float4*)(xb + voff);
        R01 = *(const float4*)(xb + voff + 4);
        voff += RST;
    } else {                               // top strip: zero-pad row
        R00 = make_float4(0.f, 0.f, 0.f, 0.f); R01 = R00;
    }
    R10 = *(const float4*)(xb + voff);     // R1 <- row rs
    R11 = *(const float4*)(xb + voff + 4);
    voff += RST;
    R20 = *(const float4*)(xb + voff);     // R2 <- row rs+1
    R21 = *(const float4*)(xb + voff + 4);
    voff += RST;
    int nextRow = rs + 2;                  // uniform: row voff points at

    float* __restrict__ ob = out + (size_t)b * H_ * OST;
    int soff = (rs * WI_ + w0 + p) * COUT + g * 4;   // dense: lane p, cout-quad g

    f4 P1 = biasF, P2 = biasF;

// load (current+3)'th row into N*, compute current row from C*
#define STEP(C0, C1, N0, N1, DS) do {                                          \
    N0 = *(const float4*)(xb + voff);                                          \
    N1 = *(const float4*)(xb + voff + 4);                                      \
    { const int inc_ = (nextRow < H_ - 1) ? RST : 0; voff += inc_; ++nextRow; }\
    __builtin_amdgcn_sched_barrier(0);                                         \
    const bh8 xf = pack_mask(C0, C1, amask);                                   \
    const f4 done = __builtin_amdgcn_mfma_f32_16x16x32_bf16(Wf2, xf, P1, 0,0,0);\
    P1 = __builtin_amdgcn_mfma_f32_16x16x32_bf16(Wf1, xf, P2, 0,0,0);          \
    P2 = __builtin_amdgcn_mfma_f32_16x16x32_bf16(Wf0, xf, biasF, 0,0,0);       \
    if (DS) {                                                                  \
        if (lane < 32) *(f4*)(ob + soff) = done;                               \
        soff += OST;                                                           \
    }                                                                          \
} while (0)

    // i=0: compute row rs-1 (R0), load rs+2 -> R3. no store.
    STEP(R00, R01, R30, R31, 0);
    // i=1: compute row rs (R1), load rs+3 -> R0. no store.
    STEP(R10, R11, R00, R01, 0);

    // i=2..61: compute rows rs+1..rs+60, store out rs..rs+59
    #pragma unroll 1
    for (int it = 0; it < 15; ++it) {
        STEP(R20, R21, R10, R11, 1);
        STEP(R30, R31, R20, R21, 1);
        STEP(R00, R01, R30, R31, 1);
        STEP(R10, R11, R00, R01, 1);
    }
    // i=62: compute rs+61 (R2), load rs+64 -> R1; store out rs+60
    STEP(R20, R21, R10, R11, 1);
    // i=63: compute rs+62 (R3); store out rs+61
    STEP(R30, R31, R20, R21, 1);
    // i=64: compute rs+63 (R0); store out rs+62
    STEP(R00, R01, R30, R31, 1);

    // out row rs+63: kh=2 term from input row rs+64 (in R1); bottom strip: zero pad
    if (rs + SS < H_) {
        const bh8 xf = pack_mask(R10, R11, amask);
        P1 = __builtin_amdgcn_mfma_f32_16x16x32_bf16(Wf2, xf, P1, 0, 0, 0);
    }
    if (lane < 32) *(f4*)(ob + soff) = P1;

#undef STEP
}

extern "C" void kernel_launch(void* const* d_in, const int* in_sizes, int n_in,
                              void* d_out, int out_size, void* d_ws, size_t ws_size,
                              hipStream_t stream) {
    const float* X    = (const float*)d_in[0];
    const float* Wt   = (const float*)d_in[1];
    const float* bias = (const float*)d_in[2];
    const float* Werr = (const float*)d_in[3];
    const float* Berr = (const float*)d_in[4];
    float* out = (float*)d_out;

    dim3 grid(WI_ / 64, H_ / SS, B_);     // (4, 4, 128)
    conv_mfma_kernel<<<grid, 256, 0, stream>>>(X, Wt, bias, Werr, Berr, out);
}

// Round 10
// 101.773 us; speedup vs baseline: 1.1882x; 1.1882x over previous
//
#include <hip/hip_runtime.h>
#include <hip/hip_bf16.h>

#define B_    128
#define H_    256
#define WI_   256
#define CIN   8
#define COUT  8
#define SS    64
#define RST   (WI_*CIN)     // 2048 f32 per input row
#define OST   (WI_*COUT)    // 2048 f32 per output row

typedef __attribute__((ext_vector_type(8))) short bh8;   // 8 bf16 (MFMA A/B frag)
typedef __attribute__((ext_vector_type(4))) float f4;    // MFMA C/D frag

static __device__ __forceinline__ unsigned short f2bf(float f) {
    union { __hip_bfloat16 h; unsigned short u; } c;
    c.h = __float2bfloat16(f);
    return c.u;
}

static __device__ __forceinline__ bh8 pack_mask(float4 lo, float4 hi, unsigned m) {
    union { bh8 v; unsigned short u[8]; unsigned w[4]; } r;
    r.u[0]=f2bf(lo.x); r.u[1]=f2bf(lo.y); r.u[2]=f2bf(lo.z); r.u[3]=f2bf(lo.w);
    r.u[4]=f2bf(hi.x); r.u[5]=f2bf(hi.y); r.u[6]=f2bf(hi.z); r.u[7]=f2bf(hi.w);
    r.w[0]&=m; r.w[1]&=m; r.w[2]&=m; r.w[3]&=m;
    return r.v;
}

// wave = 16-column output segment marching down SS rows.
// MFMA: D = Wfrag(A, M=cout) x Xfrag(B, N=pixel) + C
//   Wfrag[kh]: lane m=lane&15 (cout, 8 real), g=lane>>4 -> kw=g (g<3), k_j=ci
//   Xfrag(h'): lane p=lane&15 (pixel), g=lane>>4 -> col=w0+p+g-1, k_j=ci
//   D: lane p=lane&15 (pixel), couts 4g..4g+3 (g<2 real) -> dense float4 store
// Depth-3 prefetch via 4 rotating named row buffers; NONTEMPORAL stores
// (R8/R9 A/B showed NT stores are load-bearing: writes bypass L2).
__global__ __launch_bounds__(256, 2)
void conv_mfma_kernel(const float* __restrict__ X,
                      const float* __restrict__ Wt,
                      const float* __restrict__ bias,
                      const float* __restrict__ Werr,
                      const float* __restrict__ Berr,
                      float* __restrict__ out)
{
    __shared__ float wlds[576];           // noisy weights, transposed [khkw][cout][cin]
    const int tid = threadIdx.x;
    const int b   = blockIdx.z;
    const int rs  = blockIdx.y * SS;

    {
        const float* we = Werr + (size_t)b * 576;
        for (int i = tid; i < 576; i += 256) {
            const int khkw = i >> 6, ci = (i >> 3) & 7, co = i & 7;
            wlds[(khkw * 8 + co) * 8 + ci] = Wt[i] * we[i];
        }
    }
    __syncthreads();

    const int lane = tid & 63, wid = tid >> 6;
    const int w0 = blockIdx.x * 64 + wid * 16;
    const int p  = lane & 15;             // pixel (B col / D col); cout slot for A
    const int g  = lane >> 4;             // k-group (kw) / D cout-quad index

    // ---- A fragments: weights, one per kh; zero for m>=8 or g==3 ----
    bh8 Wf0, Wf1, Wf2;
    {
        const float4 z4 = make_float4(0.f, 0.f, 0.f, 0.f);
        #pragma unroll
        for (int kh = 0; kh < 3; ++kh) {
            float4 lo = z4, hi = z4;
            if (p < 8 && g < 3) {
                const float* ptr = &wlds[((kh * 3 + g) * 8 + p) * 8];
                lo = *(const float4*)ptr;
                hi = *(const float4*)(ptr + 4);
            }
            const bh8 f = pack_mask(lo, hi, 0xffffffffu);
            if (kh == 0) Wf0 = f; else if (kh == 1) Wf1 = f; else Wf2 = f;
        }
    }

    // ---- bias fragment: D reg r holds cout 4*g+r (g<2) ----
    f4 biasF = {0.f, 0.f, 0.f, 0.f};
    if (g < 2) {
        #pragma unroll
        for (int r = 0; r < 4; ++r) {
            const int co = g * 4 + r;
            biasF[r] = bias[co] * Berr[(size_t)b * COUT + co];
        }
    }

    // ---- X (pixel) addressing: per-lane column, clamped + masked ----
    const int col = w0 + p + g - 1;
    const unsigned amask = ((unsigned)col < (unsigned)WI_ && g < 3) ? 0xffffffffu : 0u;
    const int colc = col < 0 ? 0 : (col > WI_ - 1 ? WI_ - 1 : col);
    const float* __restrict__ xb = X + (size_t)b * H_ * RST;
    int voff = (rs > 0 ? rs - 1 : rs) * RST + colc * CIN;

    float4 R00, R01, R10, R11, R20, R21, R30, R31;
    if (rs > 0) {                          // R0 <- row rs-1
        R00 = *(const float4*)(xb + voff);
        R01 = *(const float4*)(xb + voff + 4);
        voff += RST;
    } else {                               // top strip: zero-pad row
        R00 = make_float4(0.f, 0.f, 0.f, 0.f); R01 = R00;
    }
    R10 = *(const float4*)(xb + voff);     // R1 <- row rs
    R11 = *(const float4*)(xb + voff + 4);
    voff += RST;
    R20 = *(const float4*)(xb + voff);     // R2 <- row rs+1
    R21 = *(const float4*)(xb + voff + 4);
    voff += RST;
    int nextRow = rs + 2;                  // uniform: row voff points at

    float* __restrict__ ob = out + (size_t)b * H_ * OST;
    int soff = (rs * WI_ + w0 + p) * COUT + g * 4;   // dense: lane p, cout-quad g

    f4 P1 = biasF, P2 = biasF;

// load (current+3)'th row into N*, compute current row from C*
#define STEP(C0, C1, N0, N1, DS) do {                                          \
    N0 = *(const float4*)(xb + voff);                                          \
    N1 = *(const float4*)(xb + voff + 4);                                      \
    { const int inc_ = (nextRow < H_ - 1) ? RST : 0; voff += inc_; ++nextRow; }\
    __builtin_amdgcn_sched_barrier(0);                                         \
    const bh8 xf = pack_mask(C0, C1, amask);                                   \
    const f4 done = __builtin_amdgcn_mfma_f32_16x16x32_bf16(Wf2, xf, P1, 0,0,0);\
    P1 = __builtin_amdgcn_mfma_f32_16x16x32_bf16(Wf1, xf, P2, 0,0,0);          \
    P2 = __builtin_amdgcn_mfma_f32_16x16x32_bf16(Wf0, xf, biasF, 0,0,0);       \
    if (DS) {                                                                  \
        if (lane < 32)                                                         \
            __builtin_nontemporal_store(done, (f4*)(ob + soff));               \
        soff += OST;                                                           \
    }                                                                          \
} while (0)

    // i=0: compute row rs-1 (R0), load rs+2 -> R3. no store.
    STEP(R00, R01, R30, R31, 0);
    // i=1: compute row rs (R1), load rs+3 -> R0. no store.
    STEP(R10, R11, R00, R01, 0);

    // i=2..61: compute rows rs+1..rs+60, store out rs..rs+59
    #pragma unroll 1
    for (int it = 0; it < 15; ++it) {
        STEP(R20, R21, R10, R11, 1);
        STEP(R30, R31, R20, R21, 1);
        STEP(R00, R01, R30, R31, 1);
        STEP(R10, R11, R00, R01, 1);
    }
    // i=62: compute rs+61 (R2), load rs+64 -> R1; store out rs+60
    STEP(R20, R21, R10, R11, 1);
    // i=63: compute rs+62 (R3); store out rs+61
    STEP(R30, R31, R20, R21, 1);
    // i=64: compute rs+63 (R0); store out rs+62
    STEP(R00, R01, R30, R31, 1);

    // out row rs+63: kh=2 term from input row rs+64 (in R1); bottom strip: zero pad
    if (rs + SS < H_) {
        const bh8 xf = pack_mask(R10, R11, amask);
        P1 = __builtin_amdgcn_mfma_f32_16x16x32_bf16(Wf2, xf, P1, 0, 0, 0);
    }
    if (lane < 32)
        __builtin_nontemporal_store(P1, (f4*)(ob + soff));

#undef STEP
}

extern "C" void kernel_launch(void* const* d_in, const int* in_sizes, int n_in,
                              void* d_out, int out_size, void* d_ws, size_t ws_size,
                              hipStream_t stream) {
    const float* X    = (const float*)d_in[0];
    const float* Wt   = (const float*)d_in[1];
    const float* bias = (const float*)d_in[2];
    const float* Werr = (const float*)d_in[3];
    const float* Berr = (const float*)d_in[4];
    float* out = (float*)d_out;

    dim3 grid(WI_ / 64, H_ / SS, B_);     // (4, 4, 128)
    conv_mfma_kernel<<<grid, 256, 0, stream>>>(X, Wt, bias, Werr, Berr, out);
}

// Round 11
// 97.071 us; speedup vs baseline: 1.2458x; 1.0484x over previous
//
#include <hip/hip_runtime.h>
#include <hip/hip_bf16.h>

#define B_    128
#define H_    256
#define WI_   256
#define CIN   8
#define COUT  8
#define SS    64
#define RST   (WI_*CIN)     // 2048 f32 per input row
#define OST   (WI_*COUT)    // 2048 f32 per output row

typedef __attribute__((ext_vector_type(8))) short bh8;   // 8 bf16 (MFMA A/B frag)
typedef __attribute__((ext_vector_type(4))) float f4;    // MFMA C/D frag

static __device__ __forceinline__ unsigned short f2bf(float f) {
    union { __hip_bfloat16 h; unsigned short u; } c;
    c.h = __float2bfloat16(f);
    return c.u;
}

static __device__ __forceinline__ bh8 pack_mask(float4 lo, float4 hi, unsigned m) {
    union { bh8 v; unsigned short u[8]; unsigned w[4]; } r;
    r.u[0]=f2bf(lo.x); r.u[1]=f2bf(lo.y); r.u[2]=f2bf(lo.z); r.u[3]=f2bf(lo.w);
    r.u[4]=f2bf(hi.x); r.u[5]=f2bf(hi.y); r.u[6]=f2bf(hi.z); r.u[7]=f2bf(hi.w);
    r.w[0]&=m; r.w[1]&=m; r.w[2]&=m; r.w[3]&=m;
    return r.v;
}

// wave = TWO adjacent 16-column subtiles (32 cols) marching down SS rows.
// MFMA: D = Wfrag(A, M=cout) x Xfrag(B, N=pixel) + C  (per subtile)
//   Wfrag[kh]: lane m=lane&15 (cout, 8 real), g=lane>>4 -> kw=g (g<3) — SHARED
//   Xfrag s:   lane p=lane&15 (pixel), col = w0 + s*16 + p + g - 1 (clamp+mask)
//   D: lane p (pixel), couts 4g..4g+3 (g<2) -> dense float4 NT store
// Depth-2 prefetch, 3 rotating named buffer-pairs; NT stores (R8 optimum).
__global__ __launch_bounds__(256, 2)
void conv_mfma_kernel(const float* __restrict__ X,
                      const float* __restrict__ Wt,
                      const float* __restrict__ bias,
                      const float* __restrict__ Werr,
                      const float* __restrict__ Berr,
                      float* __restrict__ out)
{
    __shared__ float wlds[576];           // noisy weights, transposed [khkw][cout][cin]
    const int tid = threadIdx.x;
    const int b   = blockIdx.z;
    const int rs  = blockIdx.y * SS;

    {
        const float* we = Werr + (size_t)b * 576;
        for (int i = tid; i < 576; i += 256) {
            const int khkw = i >> 6, ci = (i >> 3) & 7, co = i & 7;
            wlds[(khkw * 8 + co) * 8 + ci] = Wt[i] * we[i];
        }
    }
    __syncthreads();

    const int lane = tid & 63, wid = tid >> 6;
    const int w0 = (blockIdx.x * 4 + wid) * 32;   // 32 cols per wave
    const int p  = lane & 15;
    const int g  = lane >> 4;

    // ---- weight fragments (shared by both subtiles) ----
    bh8 Wf0, Wf1, Wf2;
    {
        const float4 z4 = make_float4(0.f, 0.f, 0.f, 0.f);
        #pragma unroll
        for (int kh = 0; kh < 3; ++kh) {
            float4 lo = z4, hi = z4;
            if (p < 8 && g < 3) {
                const float* ptr = &wlds[((kh * 3 + g) * 8 + p) * 8];
                lo = *(const float4*)ptr;
                hi = *(const float4*)(ptr + 4);
            }
            const bh8 f = pack_mask(lo, hi, 0xffffffffu);
            if (kh == 0) Wf0 = f; else if (kh == 1) Wf1 = f; else Wf2 = f;
        }
    }

    f4 biasF = {0.f, 0.f, 0.f, 0.f};
    if (g < 2) {
        #pragma unroll
        for (int r = 0; r < 4; ++r) {
            const int co = g * 4 + r;
            biasF[r] = bias[co] * Berr[(size_t)b * COUT + co];
        }
    }

    // ---- per-subtile column addressing ----
    const int colA = w0 + p + g - 1;
    const int colB = colA + 16;
    const unsigned maskA = ((unsigned)colA < (unsigned)WI_ && g < 3) ? 0xffffffffu : 0u;
    const unsigned maskB = ((unsigned)colB < (unsigned)WI_ && g < 3) ? 0xffffffffu : 0u;
    const int colcA = colA < 0 ? 0 : (colA > WI_ - 1 ? WI_ - 1 : colA);
    const int colcB = colB < 0 ? 0 : (colB > WI_ - 1 ? WI_ - 1 : colB);
    const int dcol  = (colcB - colcA) * CIN;      // per-lane constant offset

    const float* __restrict__ xb = X + (size_t)b * H_ * RST;
    int voff = (rs > 0 ? rs - 1 : rs) * RST + colcA * CIN;

    float4 R0a0,R0a1,R0b0,R0b1, R1a0,R1a1,R1b0,R1b1, R2a0,R2a1,R2b0,R2b1;
    if (rs > 0) {                          // R0 <- row rs-1
        R0a0 = *(const float4*)(xb + voff);        R0a1 = *(const float4*)(xb + voff + 4);
        R0b0 = *(const float4*)(xb + voff + dcol); R0b1 = *(const float4*)(xb + voff + dcol + 4);
        voff += RST;
    } else {
        R0a0 = make_float4(0.f,0.f,0.f,0.f); R0a1 = R0a0; R0b0 = R0a0; R0b1 = R0a0;
    }
    R1a0 = *(const float4*)(xb + voff);        R1a1 = *(const float4*)(xb + voff + 4);
    R1b0 = *(const float4*)(xb + voff + dcol); R1b1 = *(const float4*)(xb + voff + dcol + 4);
    voff += RST;
    int nextRow = rs + 1;

    float* __restrict__ ob = out + (size_t)b * H_ * OST;
    int soff = (rs * WI_ + w0 + p) * COUT + g * 4;   // subtile A; B = +16*COUT

    f4 P1a = biasF, P2a = biasF, P1b = biasF, P2b = biasF;

#define STEP(Ca0,Ca1,Cb0,Cb1, Na0,Na1,Nb0,Nb1, DS) do {                        \
    Na0 = *(const float4*)(xb + voff);                                         \
    Na1 = *(const float4*)(xb + voff + 4);                                     \
    Nb0 = *(const float4*)(xb + voff + dcol);                                  \
    Nb1 = *(const float4*)(xb + voff + dcol + 4);                              \
    { const int inc_ = (nextRow < H_ - 1) ? RST : 0; voff += inc_; ++nextRow; }\
    __builtin_amdgcn_sched_barrier(0);                                         \
    const bh8 xfa = pack_mask(Ca0, Ca1, maskA);                                \
    const bh8 xfb = pack_mask(Cb0, Cb1, maskB);                                \
    const f4 dA = __builtin_amdgcn_mfma_f32_16x16x32_bf16(Wf2, xfa, P1a, 0,0,0);\
    const f4 dB = __builtin_amdgcn_mfma_f32_16x16x32_bf16(Wf2, xfb, P1b, 0,0,0);\
    P1a = __builtin_amdgcn_mfma_f32_16x16x32_bf16(Wf1, xfa, P2a, 0,0,0);       \
    P1b = __builtin_amdgcn_mfma_f32_16x16x32_bf16(Wf1, xfb, P2b, 0,0,0);       \
    P2a = __builtin_amdgcn_mfma_f32_16x16x32_bf16(Wf0, xfa, biasF, 0,0,0);     \
    P2b = __builtin_amdgcn_mfma_f32_16x16x32_bf16(Wf0, xfb, biasF, 0,0,0);     \
    if (DS) {                                                                  \
        if (lane < 32) {                                                       \
            __builtin_nontemporal_store(dA, (f4*)(ob + soff));                 \
            __builtin_nontemporal_store(dB, (f4*)(ob + soff + 16*COUT));       \
        }                                                                      \
        soff += OST;                                                           \
    }                                                                          \
} while (0)

    // i=0: compute rs-1 (R0), load rs+1 -> R2. no store.
    STEP(R0a0,R0a1,R0b0,R0b1, R2a0,R2a1,R2b0,R2b1, 0);
    // i=1: compute rs (R1), load rs+2 -> R0. no store.
    STEP(R1a0,R1a1,R1b0,R1b1, R0a0,R0a1,R0b0,R0b1, 0);

    // i=2..64: compute rs+1..rs+63, store out rs..rs+62
    #pragma unroll 1
    for (int it = 0; it < 21; ++it) {
        STEP(R2a0,R2a1,R2b0,R2b1, R1a0,R1a1,R1b0,R1b1, 1);
        STEP(R0a0,R0a1,R0b0,R0b1, R2a0,R2a1,R2b0,R2b1, 1);
        STEP(R1a0,R1a1,R1b0,R1b1, R0a0,R0a1,R0b0,R0b1, 1);
    }

    // out row rs+63: kh=2 term from input row rs+64 (held in R2 pair)
    if (rs + SS < H_) {
        const bh8 xfa = pack_mask(R2a0, R2a1, maskA);
        const bh8 xfb = pack_mask(R2b0, R2b1, maskB);
        P1a = __builtin_amdgcn_mfma_f32_16x16x32_bf16(Wf2, xfa, P1a, 0, 0, 0);
        P1b = __builtin_amdgcn_mfma_f32_16x16x32_bf16(Wf2, xfb, P1b, 0, 0, 0);
    }
    if (lane < 32) {
        __builtin_nontemporal_store(P1a, (f4*)(ob + soff));
        __builtin_nontemporal_store(P1b, (f4*)(ob + soff + 16*COUT));
    }

#undef STEP
}

extern "C" void kernel_launch(void* const* d_in, const int* in_sizes, int n_in,
                              void* d_out, int out_size, void* d_ws, size_t ws_size,
                              hipStream_t stream) {
    const float* X    = (const float*)d_in[0];
    const float* Wt   = (const float*)d_in[1];
    const float* bias = (const float*)d_in[2];
    const float* Werr = (const float*)d_in[3];
    const float* Berr = (const float*)d_in[4];
    float* out = (float*)d_out;

    dim3 grid(WI_ / 128, H_ / SS, B_);    // (2, 4, 128) = 1024 blocks
    conv_mfma_kernel<<<grid, 256, 0, stream>>>(X, Wt, bias, Werr, Berr, out);
}